// Round 4
// baseline (185.783 us; speedup 1.0000x reference)
//
#include <hip/hip_runtime.h>
#include <hip/hip_bf16.h>

// GAT attention aggregator, fused. B=20000, N=32, D=128, H=256, O=128.
// MB=4 nodes per block. Score matmul + softmax + aggregation + output matmul
// in one kernel, bf16 MFMA 16x16x32. OUTPUT IS FLOAT32 (reference returns
// f32; earlier rounds wrongly wrote bf16 shorts -> harness read zeros/garbage).

#define BB 20000
#define NN 32
#define DD 128
#define HH 256
#define OO 128
#define MB 4
#define NR (MB * NN)     // 128 neighbor rows
#define ROWS 144         // 128 neib + 4 x + 4 agg + 8 pad
#define XR0 128          // x rows 128..131
#define AG0 132          // agg rows 132..135 (136..143 zero pad)

typedef __bf16 bf16x8 __attribute__((ext_vector_type(8)));
typedef float f32x4 __attribute__((ext_vector_type(4)));

__device__ __forceinline__ unsigned short f2bf(float f) {
    unsigned u = __builtin_bit_cast(unsigned, f);
    u += 0x7fffu + ((u >> 16) & 1u);     // round-to-nearest-even
    return (unsigned short)(u >> 16);
}
__device__ __forceinline__ float bf2f(unsigned short s) {
    return __builtin_bit_cast(float, ((unsigned)s) << 16);
}

__global__ void prep_weights(const float* __restrict__ Watt,
                             const float* __restrict__ Wfcx,
                             const float* __restrict__ Wfcn,
                             unsigned short* __restrict__ WaT,
                             unsigned short* __restrict__ WcT) {
    int idx = blockIdx.x * 256 + threadIdx.x;   // 0..65535
    int half = idx >> 15;                        // 0: WaT, 1: WcT
    int j = idx & 32767;
    int c = j >> 7, k = j & 127;                 // c in 0..255, k in 0..127
    if (half == 0) {
        WaT[j] = f2bf(Watt[k * HH + c]);         // WaT[h][k] = W_att[k][h]
    } else {
        float w = (c < OO) ? Wfcx[k * OO + c] : Wfcn[k * OO + (c - OO)];
        WcT[j] = f2bf(w);                        // WcT[c][k]
    }
}

__launch_bounds__(256, 2)
__global__ void gat_fused(const float* __restrict__ x,
                          const float* __restrict__ neibs,
                          const float* __restrict__ a,
                          const unsigned short* __restrict__ WaT,
                          const unsigned short* __restrict__ WcT,
                          float* __restrict__ out) {
    __shared__ unsigned short rowsS[ROWS * 128]; // 36,864 B, XOR-swizzled rows
    __shared__ float e_part[4][ROWS];            //  2,304 B
    __shared__ float att_s[MB][NN];              //    512 B

    const int tid = threadIdx.x;
    const int w   = tid >> 6;      // wave id 0..3
    const int l   = tid & 63;      // lane
    const int lr  = l & 15;        // fragment row/col-in-tile
    const int lg  = l >> 4;        // k-group
    const int b0  = blockIdx.x * MB;
    char* rbase = (char*)rowsS;

    // ---- hoist B fragments for score matmul (W_att^T, L2-resident) ----
    bf16x8 bfr[4][4];
    float aN[4], aX[4];
#pragma unroll
    for (int c4 = 0; c4 < 4; ++c4) {
        int col = (w * 4 + c4) * 16 + lr;
#pragma unroll
        for (int ks = 0; ks < 4; ++ks)
            bfr[c4][ks] = *(const bf16x8*)(WaT + col * 128 + ks * 32 + lg * 8);
        aX[c4] = a[col];
        aN[c4] = a[HH + col];
    }

    // ---- stage rows into swizzled LDS as bf16 ----
    {
        const float4* np4 = (const float4*)(neibs + (size_t)b0 * NN * DD);
#pragma unroll 8
        for (int it = 0; it < 16; ++it) {
            int i4 = it * 256 + tid;          // float4 index, 0..4095
            float4 v = np4[i4];
            int o = i4 * 4;
            int row = o >> 7, k = o & 127;    // row = b_local*32+n
            unsigned off = (unsigned)(row * 256 + 2 * k) ^ ((row & 7) << 4);
            ushort4 s4 = { f2bf(v.x), f2bf(v.y), f2bf(v.z), f2bf(v.w) };
            *(ushort4*)(rbase + off) = s4;
        }
        // x rows -> 128..131 (threads 0..127)
        if (tid < 128) {
            const float4* xp4 = (const float4*)(x + (size_t)b0 * DD);
            float4 v = xp4[tid];
            int o = tid * 4;
            int row = XR0 + (o >> 7), k = o & 127;
            unsigned off = (unsigned)(row * 256 + 2 * k) ^ ((row & 7) << 4);
            ushort4 s4 = { f2bf(v.x), f2bf(v.y), f2bf(v.z), f2bf(v.w) };
            *(ushort4*)(rbase + off) = s4;
        }
        // zero rows 132..143 (12 rows x 32 ushort4 slots = 384)
#pragma unroll
        for (int r2 = 0; r2 < 2; ++r2) {
            int slot = r2 * 256 + tid;
            if (slot < 384) {
                int row = AG0 + (slot >> 5), k4 = slot & 31;
                unsigned off = (unsigned)(row * 256 + 8 * k4) ^ ((row & 7) << 4);
                ushort4 z4 = { 0, 0, 0, 0 };
                *(ushort4*)(rbase + off) = z4;
            }
        }
    }
    __syncthreads();

    // ---- score matmul: R[144x128] @ WaT^T -> lrelu(.01) -> dot a -> e partials ----
#pragma unroll 1
    for (int rt = 0; rt < 9; ++rt) {
        int arow = rt * 16 + lr;
        bf16x8 af[4];
#pragma unroll
        for (int ks = 0; ks < 4; ++ks) {
            unsigned off = (unsigned)(arow * 256 + ks * 64 + lg * 16) ^ ((arow & 7) << 4);
            af[ks] = *(const bf16x8*)(rbase + off);
        }
        f32x4 acc[4];
#pragma unroll
        for (int c4 = 0; c4 < 4; ++c4) acc[c4] = (f32x4){0.f, 0.f, 0.f, 0.f};
#pragma unroll
        for (int c4 = 0; c4 < 4; ++c4)
#pragma unroll
            for (int ks = 0; ks < 4; ++ks)
                acc[c4] = __builtin_amdgcn_mfma_f32_16x16x32_bf16(af[ks], bfr[c4][ks], acc[c4], 0, 0, 0);

        float ep[4] = {0.f, 0.f, 0.f, 0.f};
        bool isx = (rt == 8);
#pragma unroll
        for (int c4 = 0; c4 < 4; ++c4) {
            float av = isx ? aX[c4] : aN[c4];
#pragma unroll
            for (int i = 0; i < 4; ++i) {
                float v = acc[c4][i];
                float lv = fmaxf(v, 0.f) + 0.01f * fminf(v, 0.f);
                ep[i] += lv * av;
            }
        }
#pragma unroll
        for (int i = 0; i < 4; ++i) {
            ep[i] += __shfl_xor(ep[i], 1, 16);
            ep[i] += __shfl_xor(ep[i], 2, 16);
            ep[i] += __shfl_xor(ep[i], 4, 16);
            ep[i] += __shfl_xor(ep[i], 8, 16);
        }
        if (lr == 0) {
#pragma unroll
            for (int i = 0; i < 4; ++i)
                e_part[w][rt * 16 + lg * 4 + i] = ep[i];
        }
    }
    __syncthreads();

    // ---- combine e, lrelu(0.2), softmax over 32 neighbors (threads 0..127) ----
    if (tid < 128) {
        const int bloc = tid >> 5;      // node 0..3
        const int nloc = tid & 31;      // neighbor
        float sn = e_part[0][tid] + e_part[1][tid] + e_part[2][tid] + e_part[3][tid];
        float sx = e_part[0][XR0 + bloc] + e_part[1][XR0 + bloc] +
                   e_part[2][XR0 + bloc] + e_part[3][XR0 + bloc];
        float e = sx + sn;
        e = (e > 0.f) ? e : 0.2f * e;
        float mx = e;
#pragma unroll
        for (int m = 16; m >= 1; m >>= 1) mx = fmaxf(mx, __shfl_xor(mx, m, 32));
        float ex = __expf(e - mx);
        float sum = ex;
#pragma unroll
        for (int m = 16; m >= 1; m >>= 1) sum += __shfl_xor(sum, m, 32);
        att_s[bloc][nloc] = ex / sum;
    }
    __syncthreads();

    // ---- aggregation: agg[b][d] = sum_n att[n]*neib[b][n][d]; all 256 threads ----
    {
        const int node = tid >> 6;        // == wave id
        const int l64  = tid & 63;        // d-pair index: d = 2*l64, 2*l64+1
        float ag0 = 0.f, ag1 = 0.f;
#pragma unroll 8
        for (int n2 = 0; n2 < 32; ++n2) {
            float wv = att_s[node][n2];
            int row = node * 32 + n2;
            unsigned off = (unsigned)(row * 256 + 4 * l64) ^ ((row & 7) << 4);
            ushort2 v2 = *(const ushort2*)(rbase + off);
            ag0 += wv * bf2f(v2.x);
            ag1 += wv * bf2f(v2.y);
        }
        int row = AG0 + node;
        unsigned off = (unsigned)(row * 256 + 4 * l64) ^ ((row & 7) << 4);
        ushort2 s2 = { f2bf(ag0), f2bf(ag1) };
        *(ushort2*)(rbase + off) = s2;
    }
    __syncthreads();

    // ---- final matmul: [x;agg;pad](16x128) @ WcT^T(128x256), masked f32 store ----
    {
        bf16x8 bff[4][4];
#pragma unroll
        for (int c4 = 0; c4 < 4; ++c4) {
            int col = (w * 4 + c4) * 16 + lr;
#pragma unroll
            for (int ks = 0; ks < 4; ++ks)
                bff[c4][ks] = *(const bf16x8*)(WcT + col * 128 + ks * 32 + lg * 8);
        }
        bf16x8 af[4];
        int arow = XR0 + lr;              // rows 128..143
#pragma unroll
        for (int ks = 0; ks < 4; ++ks) {
            unsigned off = (unsigned)(arow * 256 + ks * 64 + lg * 16) ^ ((arow & 7) << 4);
            af[ks] = *(const bf16x8*)(rbase + off);
        }
#pragma unroll
        for (int c4 = 0; c4 < 4; ++c4) {
            f32x4 acc = (f32x4){0.f, 0.f, 0.f, 0.f};
#pragma unroll
            for (int ks = 0; ks < 4; ++ks)
                acc = __builtin_amdgcn_mfma_f32_16x16x32_bf16(af[ks], bff[c4][ks], acc, 0, 0, 0);
            int col = (w * 4 + c4) * 16 + lr;
#pragma unroll
            for (int reg = 0; reg < 4; ++reg) {
                int i = lg * 4 + reg;     // C row: 0..3 x rows, 4..7 agg rows
                bool doit = (col < 128) ? (i < 4) : (i >= 4 && i < 8);
                if (doit) {
                    float v = fmaxf(acc[reg], 0.f);
                    out[(size_t)(b0 + (i & 3)) * 256 + col] = v;
                }
            }
        }
    }
}

extern "C" void kernel_launch(void* const* d_in, const int* in_sizes, int n_in,
                              void* d_out, int out_size, void* d_ws, size_t ws_size,
                              hipStream_t stream) {
    const float* x    = (const float*)d_in[0];
    const float* nb   = (const float*)d_in[1];
    const float* Watt = (const float*)d_in[2];
    const float* Wfcx = (const float*)d_in[3];
    const float* Wfcn = (const float*)d_in[4];
    const float* a    = (const float*)d_in[5];
    unsigned short* WaT = (unsigned short*)d_ws;
    unsigned short* WcT = WaT + 128 * 256;
    float* o = (float*)d_out;

    prep_weights<<<256, 256, 0, stream>>>(Watt, Wfcx, Wfcn, WaT, WcT);
    gat_fused<<<BB / MB, 256, 0, stream>>>(x, nb, a, WaT, WcT, o);
}

// Round 5
// 132.812 us; speedup vs baseline: 1.3988x; 1.3988x over previous
//
#include <hip/hip_runtime.h>
#include <hip/hip_bf16.h>

// GAT attention aggregator, fused. B=20000, N=32, D=128, H=256, O=128.
// MB=4 nodes/block, 5000 blocks. R5: latency attack — hoisted swizzle bases
// (all LDS offsets become immediates under full unroll), DPP row_shr reduce
// instead of shfl_xor, (__bf16) casts instead of manual f2bf, half-wave
// aggregation, launch_bounds(256,4) for 4 blocks/CU.

#define BB 20000
#define NN 32
#define DD 128
#define HH 256
#define OO 128
#define MB 4
#define ROWS 144         // 128 neib + 4 x + 4 agg + 8 pad (pad left garbage)
#define XR0 128
#define AG0 132

typedef __bf16 bf16x8 __attribute__((ext_vector_type(8)));
typedef __bf16 bf16x4 __attribute__((ext_vector_type(4)));
typedef float f32x4 __attribute__((ext_vector_type(4)));

template<int CTRL>
__device__ __forceinline__ float dpp_add(float v) {
    int r = __builtin_amdgcn_update_dpp(0, __builtin_bit_cast(int, v), CTRL, 0xF, 0xF, true);
    return v + __builtin_bit_cast(float, r);
}
// after this, lane 15 of each 16-lane row holds the row sum
__device__ __forceinline__ float red16(float v) {
    v = dpp_add<0x111>(v);   // row_shr:1
    v = dpp_add<0x112>(v);   // row_shr:2
    v = dpp_add<0x114>(v);   // row_shr:4
    v = dpp_add<0x118>(v);   // row_shr:8
    return v;
}

__global__ void prep_weights(const float* __restrict__ Watt,
                             const float* __restrict__ Wfcx,
                             const float* __restrict__ Wfcn,
                             __bf16* __restrict__ WaT,
                             __bf16* __restrict__ WcT) {
    int idx = blockIdx.x * 256 + threadIdx.x;   // 0..65535
    int half = idx >> 15;                        // 0: WaT, 1: WcT
    int j = idx & 32767;
    int c = j >> 7, k = j & 127;
    if (half == 0) {
        WaT[j] = (__bf16)Watt[k * HH + c];        // WaT[h][k] = W_att[k][h]
    } else {
        float wv = (c < OO) ? Wfcx[k * OO + c] : Wfcn[k * OO + (c - OO)];
        WcT[j] = (__bf16)wv;                      // WcT[c][k]
    }
}

__launch_bounds__(256, 4)
__global__ void gat_fused(const float* __restrict__ x,
                          const float* __restrict__ neibs,
                          const float* __restrict__ a,
                          const __bf16* __restrict__ WaT,
                          const __bf16* __restrict__ WcT,
                          float* __restrict__ out) {
    __shared__ __bf16 rowsS[ROWS * 128];         // 36,864 B, XOR-swizzled rows
    __shared__ float e_part[4][ROWS];            //  2,304 B
    __shared__ float att_s[MB][NN];              //    512 B

    const int tid = threadIdx.x;
    const int w   = tid >> 6;      // wave id 0..3
    const int l   = tid & 63;      // lane
    const int lr  = l & 15;        // fragment row/col-in-tile
    const int lg  = l >> 4;        // k-group
    const int b0  = blockIdx.x * MB;
    char* rbase = (char*)rowsS;

    // ---- stage 128 neib rows + 4 x rows into swizzled LDS as bf16 ----
    // byte off for (row, elem k): (row*256 + 2k) ^ ((row&7)<<4)
    // staging row = it*8 + tid>>5 -> row&7 = tid>>5 (invariant)
    const int stbase = (tid >> 5) * 256 + ((8 * (tid & 31)) ^ ((tid >> 5) << 4));
    {
        const float4* np4 = (const float4*)(neibs + (size_t)b0 * NN * DD);
#pragma unroll
        for (int it = 0; it < 16; ++it) {
            float4 v = np4[it * 256 + tid];
            bf16x4 s = { (__bf16)v.x, (__bf16)v.y, (__bf16)v.z, (__bf16)v.w };
            *(bf16x4*)(rbase + stbase + it * 2048) = s;
        }
        if (tid < 128) {   // x rows 128..131: same base, +128*256
            const float4* xp4 = (const float4*)(x + (size_t)b0 * DD);
            float4 v = xp4[tid];
            bf16x4 s = { (__bf16)v.x, (__bf16)v.y, (__bf16)v.z, (__bf16)v.w };
            *(bf16x4*)(rbase + stbase + 32768) = s;
        }
    }

    // ---- hoist B fragments for score matmul (W_att^T, L2-resident) ----
    bf16x8 bfr[4][4];
    float aN[4], aNs[4], aX[4], aXs[4];
#pragma unroll
    for (int c4 = 0; c4 < 4; ++c4) {
        int col = (w * 4 + c4) * 16 + lr;
#pragma unroll
        for (int ks = 0; ks < 4; ++ks)
            bfr[c4][ks] = *(const bf16x8*)(WaT + col * 128 + ks * 32 + lg * 8);
        aX[c4] = a[col];        aXs[c4] = aX[c4] * 0.01f;
        aN[c4] = a[HH + col];   aNs[c4] = aN[c4] * 0.01f;
    }

    // A-fragment swizzle bases: arow = rt*16 + lr -> arow&7 = lr&7 (invariant)
    int abase[4];
#pragma unroll
    for (int ks = 0; ks < 4; ++ks)
        abase[ks] = lr * 256 + ((ks * 64 + lg * 16) ^ ((lr & 7) << 4));

    __syncthreads();

    // ---- score matmul: 9 row-tiles x (4 col-tiles x 4 k) MFMA, fused lrelu.a reduce ----
#pragma unroll
    for (int rt = 0; rt < 9; ++rt) {
        bf16x8 af[4];
#pragma unroll
        for (int ks = 0; ks < 4; ++ks)
            af[ks] = *(const bf16x8*)(rbase + abase[ks] + rt * 4096);
        f32x4 acc[4];
#pragma unroll
        for (int c4 = 0; c4 < 4; ++c4) acc[c4] = (f32x4){0.f, 0.f, 0.f, 0.f};
#pragma unroll
        for (int c4 = 0; c4 < 4; ++c4)
#pragma unroll
            for (int ks = 0; ks < 4; ++ks)
                acc[c4] = __builtin_amdgcn_mfma_f32_16x16x32_bf16(af[ks], bfr[c4][ks], acc[c4], 0, 0, 0);

        float ep[4] = {0.f, 0.f, 0.f, 0.f};
#pragma unroll
        for (int c4 = 0; c4 < 4; ++c4) {
            float av  = (rt == 8) ? aX[c4]  : aN[c4];
            float avs = (rt == 8) ? aXs[c4] : aNs[c4];
#pragma unroll
            for (int i = 0; i < 4; ++i) {
                float v = acc[c4][i];
                ep[i] = fmaf(v, (v > 0.f) ? av : avs, ep[i]);
            }
        }
#pragma unroll
        for (int i = 0; i < 4; ++i) ep[i] = red16(ep[i]);
        if (lr == 15) {   // lanes 15,31,47,63 hold sums for lg = 0..3
            f32x4 st = { ep[0], ep[1], ep[2], ep[3] };
            *(f32x4*)((char*)&e_part[w][0] + rt * 64 + lg * 16) = st;
        }
    }
    __syncthreads();

    // ---- combine e, lrelu(0.2), softmax over 32 neighbors (threads 0..127) ----
    if (tid < 128) {
        const int bloc = tid >> 5;
        const int nloc = tid & 31;
        float sn = e_part[0][tid] + e_part[1][tid] + e_part[2][tid] + e_part[3][tid];
        float sx = e_part[0][XR0 + bloc] + e_part[1][XR0 + bloc] +
                   e_part[2][XR0 + bloc] + e_part[3][XR0 + bloc];
        float e = sx + sn;
        e = (e > 0.f) ? e : 0.2f * e;
        float mx = e;
#pragma unroll
        for (int m = 16; m >= 1; m >>= 1) mx = fmaxf(mx, __shfl_xor(mx, m, 32));
        float ex = __expf(e - mx);
        float sum = ex;
#pragma unroll
        for (int m = 16; m >= 1; m >>= 1) sum += __shfl_xor(sum, m, 32);
        att_s[bloc][nloc] = ex / sum;
    }
    __syncthreads();

    // ---- load final-matmul B fragments early (L2 latency hides under agg) ----
    bf16x8 bff[4][4];
#pragma unroll
    for (int c4 = 0; c4 < 4; ++c4) {
        int col = (w * 4 + c4) * 16 + lr;
#pragma unroll
        for (int ks = 0; ks < 4; ++ks)
            bff[c4][ks] = *(const bf16x8*)(WcT + col * 128 + ks * 32 + lg * 8);
    }

    // ---- aggregation: wave w = node w; half-waves take even/odd neighbors ----
    {
        const int half = l >> 5, li = l & 31;
        const int node = w;
        // row = node*32 + (2i+half); elem d = 4*li..4*li+3 (8 bytes)
        const int agbase = node * 8192 + 256 * half + ((8 * li) ^ (half << 4));
        float ag[4] = {0.f, 0.f, 0.f, 0.f};
#pragma unroll
        for (int i = 0; i < 16; ++i) {
            float wv = att_s[node][2 * i + half];
            bf16x4 v = *(const bf16x4*)(rbase + (agbase ^ ((2 * i & 7) << 4)) + 512 * i);
#pragma unroll
            for (int j = 0; j < 4; ++j) ag[j] = fmaf(wv, (float)v[j], ag[j]);
        }
#pragma unroll
        for (int j = 0; j < 4; ++j) ag[j] += __shfl_xor(ag[j], 32);
        if (half == 0) {
            int row = AG0 + node;    // row&7 = 4+node
            int off = row * 256 + ((8 * li) ^ ((row & 7) << 4));
            bf16x4 s = { (__bf16)ag[0], (__bf16)ag[1], (__bf16)ag[2], (__bf16)ag[3] };
            *(bf16x4*)(rbase + off) = s;
        }
    }
    __syncthreads();

    // ---- final matmul: [x;agg;junk](16x128) @ WcT^T(128x256), masked f32 store ----
    {
        bf16x8 af[4];
#pragma unroll
        for (int ks = 0; ks < 4; ++ks)
            af[ks] = *(const bf16x8*)(rbase + abase[ks] + 32768);  // rows 128+lr
#pragma unroll
        for (int c4 = 0; c4 < 4; ++c4) {
            f32x4 acc = (f32x4){0.f, 0.f, 0.f, 0.f};
#pragma unroll
            for (int ks = 0; ks < 4; ++ks)
                acc = __builtin_amdgcn_mfma_f32_16x16x32_bf16(af[ks], bff[c4][ks], acc, 0, 0, 0);
            int col = (w * 4 + c4) * 16 + lr;
#pragma unroll
            for (int reg = 0; reg < 4; ++reg) {
                int i = lg * 4 + reg;     // C row: 0..3 = x rows, 4..7 = agg rows
                bool doit = (col < 128) ? (i < 4) : (i >= 4 && i < 8);
                if (doit) {
                    float v = fmaxf(acc[reg], 0.f);
                    out[(size_t)(b0 + (i & 3)) * 256 + col] = v;
                }
            }
        }
    }
}

extern "C" void kernel_launch(void* const* d_in, const int* in_sizes, int n_in,
                              void* d_out, int out_size, void* d_ws, size_t ws_size,
                              hipStream_t stream) {
    const float* x    = (const float*)d_in[0];
    const float* nb   = (const float*)d_in[1];
    const float* Watt = (const float*)d_in[2];
    const float* Wfcx = (const float*)d_in[3];
    const float* Wfcn = (const float*)d_in[4];
    const float* a    = (const float*)d_in[5];
    __bf16* WaT = (__bf16*)d_ws;
    __bf16* WcT = WaT + 128 * 256;
    float* o = (float*)d_out;

    prep_weights<<<256, 256, 0, stream>>>(Watt, Wfcx, Wfcn, WaT, WcT);
    gat_fused<<<BB / MB, 256, 0, stream>>>(x, nb, a, WaT, WcT, o);
}